// Round 8
// baseline (97.943 us; speedup 1.0000x reference)
//
#include <hip/hip_runtime.h>

typedef unsigned short u16;
typedef short short8 __attribute__((ext_vector_type(8)));
typedef float f32x4 __attribute__((ext_vector_type(4)));

#define SLEN 2048
#define QKV_LD 3072
#define KOFF 2048
#define VOFF 2560

__device__ __forceinline__ u16 f2b(float f){
  unsigned u = __float_as_uint(f);
  u = u + 0x7FFFu + ((u >> 16) & 1u);     // RNE f32 -> bf16
  return (u16)(u >> 16);
}
__device__ __forceinline__ float b2f(u16 v){
  unsigned u = ((unsigned)v) << 16;
  return __uint_as_float(u);
}

__device__ __forceinline__ void gload16(const u16* g, u16* l){
  __builtin_amdgcn_global_load_lds((const __attribute__((address_space(1))) void*)g,
                                   (__attribute__((address_space(3))) void*)l, 16, 0, 0);
}

// ---------------- fused prep: hidden f2b (b<4096) + rope table (4096..4223) + weight transposes
__global__ __launch_bounds__(256) void k_prep(const float* __restrict__ hidden, u16* __restrict__ hb,
                                              const int* __restrict__ pos, float* __restrict__ g,
                                              const float* __restrict__ Wq, const float* __restrict__ Wk,
                                              const float* __restrict__ Wv, const float* __restrict__ Wo,
                                              u16* __restrict__ Wcat, u16* __restrict__ Wot){
  __shared__ float tile[64][68];
  int b = blockIdx.x, t = threadIdx.x;
  if (b < 4096){
    int i = b * 256 + t;
    float4 v = ((const float4*)hidden)[i];
    ushort4 o;
    o.x = f2b(v.x); o.y = f2b(v.y); o.z = f2b(v.z); o.w = f2b(v.w);
    ((ushort4*)hb)[i] = o;
    return;
  }
  if (b < 4224){
    int idx = (b - 4096) * 256 + t;
    int s = idx >> 4, i = idx & 15;
    float inv = 1.0f / powf(150000.0f, (float)i / 16.0f);
    float wl = 6.283185307179586f / inv;
    float ratio = 4096.0f / wl;
    float alpha = (32.0f * ratio - 32.0f) / (1.0f - 32.0f);
    alpha = fminf(fmaxf(alpha, 0.0f), 1.0f);
    float invs = inv / powf(32.0f, alpha);
    float th = (float)pos[s] * invs;
    double tt = (double)th;
    g[idx] = (float)(cos(tt) + sin(tt));
    return;
  }
  b -= 4224;
  const float* W; u16* D; int Nw, rowoff;
  if (b < 1024)      { W = Wq; D = Wcat; Nw = 2048; rowoff = 0; }
  else if (b < 1280) { W = Wk; D = Wcat; Nw = 512;  rowoff = 2048; b -= 1024; }
  else if (b < 1536) { W = Wv; D = Wcat; Nw = 512;  rowoff = 2560; b -= 1280; }
  else               { W = Wo; D = Wot;  Nw = 2048; rowoff = 0;    b -= 1536; }
  const int kt = b & 31, nt = b >> 5;
  const int k0 = kt * 64, n0 = nt * 64;
  #pragma unroll
  for (int i = 0; i < 4; ++i){
    int slot = i * 256 + t;
    int r = slot >> 4, c4 = (slot & 15) * 4;
    float4 v = *(const float4*)&W[(size_t)(k0 + r) * Nw + n0 + c4];
    tile[r][c4] = v.x; tile[r][c4+1] = v.y; tile[r][c4+2] = v.z; tile[r][c4+3] = v.w;
  }
  __syncthreads();
  #pragma unroll
  for (int i = 0; i < 4; ++i){
    int slot = i * 256 + t;
    int nl = slot >> 4, k4 = (slot & 15) * 4;
    ushort4 o;
    o.x = f2b(tile[k4][nl]);   o.y = f2b(tile[k4+1][nl]);
    o.z = f2b(tile[k4+2][nl]); o.w = f2b(tile[k4+3][nl]);
    *(ushort4*)&D[(size_t)(rowoff + n0 + nl) * 2048 + k0 + k4] = o;
  }
}

// ---------------- GEMM: parameterized BMxBN block, BK=64, 4 waves (2x2 wave grid,
// wave tile BM/2 x BN/2), gload_lds-16B, XOR-8 source-side swizzle, counted vmcnt,
// XCD swizzle. 512-block grids = 2 blocks/CU, one clean co-residency round.
//   QKV (M2048,N3072): BM=128,BN=96  -> 512 blocks (R2-validated ~38us)
//   out (M2048,N2048): BM=64, BN=128 -> 512 blocks (R1-validated ~21.6us)
// R8: Q-scale folds log2e (0.125*1.442695) so attn softmax can use exp2 directly.
template<int OUTF32, int ROPE, int BM, int BN, int MINW>
__global__ __launch_bounds__(256, MINW) void k_gemm(const u16* __restrict__ A, const u16* __restrict__ Bt,
                                                    void* __restrict__ C, const float* __restrict__ g,
                                                    int M, int N, int K){
  constexpr int AG = BM / 32;               // A gload_lds per wave per stage
  constexpr int BG = BN / 32;               // B gload_lds per wave per stage
  constexpr int ASZ = BM * 64;              // u16 per A buffer
  constexpr int BSZ = BN * 64;              // u16 per B buffer
  constexpr int MR = BM / 32;               // 16-row fragments per wave tile
  constexpr int NR = BN / 32;               // 16-col fragments per wave tile
  __shared__ __align__(16) u16 Smem[2 * (ASZ + BSZ)];
  const int tid = threadIdx.x;
  const int lane = tid & 63;
  const int w = tid >> 6;                   // 0..3
  const int wr = (w >> 1) * (BM / 2);
  const int wc = (w & 1) * (BN / 2);

  const int nbx = M / BM;
  const int nb  = nbx * (N / BN);
  const int q8  = nb >> 3;
  const int bo  = blockIdx.x;
  const int id2 = (bo & 7) * q8 + (bo >> 3);
  const int m0 = (id2 % nbx) * BM;
  const int n0 = (id2 / nbx) * BN;

  const int rl = lane >> 3;
  const int sc = ((lane & 7) ^ rl) << 3;
  const u16* Ag[AG]; const u16* Bg[BG];
  int Ad[AG], Bd[BG];
  #pragma unroll
  for (int i = 0; i < AG; ++i){
    int row0 = w * (AG * 8) + i * 8;        // A rows 0..BM-1 across 4 waves
    Ag[i] = A + (size_t)(m0 + row0 + rl) * K + sc;
    Ad[i] = row0 * 64;
  }
  #pragma unroll
  for (int i = 0; i < BG; ++i){
    int row0 = w * (BG * 8) + i * 8;        // B rows 0..BN-1 across 4 waves
    Bg[i] = Bt + (size_t)(n0 + row0 + rl) * K + sc;
    Bd[i] = 2 * ASZ + row0 * 64;
  }

  const int fr = lane & 15;
  const int g4 = lane >> 4;

  f32x4 acc[MR][NR] = {};

  auto stage = [&](int buf, int k0){
    #pragma unroll
    for (int i = 0; i < AG; ++i) gload16(Ag[i] + k0, Smem + Ad[i] + buf * ASZ);
    #pragma unroll
    for (int i = 0; i < BG; ++i) gload16(Bg[i] + k0, Smem + Bd[i] + buf * BSZ);
  };

  stage(0, 0);
  int buf = 0;
  const int nt = K >> 6;
  for (int kt = 0; kt < nt; ++kt){
    if (kt + 1 < nt){
      stage(buf ^ 1, (kt + 1) << 6);
      if constexpr (AG + BG == 6)      asm volatile("s_waitcnt vmcnt(6)" ::: "memory");
      else if constexpr (AG + BG == 7) asm volatile("s_waitcnt vmcnt(7)" ::: "memory");
      else                             asm volatile("s_waitcnt vmcnt(8)" ::: "memory");
    } else {
      asm volatile("s_waitcnt vmcnt(0)" ::: "memory");
    }
    __builtin_amdgcn_s_barrier();
    __builtin_amdgcn_sched_barrier(0);
    {
      const u16* Asb = Smem + buf * ASZ;
      const u16* Bsb = Smem + 2 * ASZ + buf * BSZ;
      #pragma unroll
      for (int kk = 0; kk < 2; ++kk){
        const int sw = (((kk * 4 + g4)) ^ (fr & 7)) << 3;
        short8 af[MR], bf[NR];
        #pragma unroll
        for (int m = 0; m < MR; ++m)
          af[m] = *(const short8*)&Asb[(wr + m * 16 + fr) * 64 + sw];
        #pragma unroll
        for (int j = 0; j < NR; ++j)
          bf[j] = *(const short8*)&Bsb[(wc + j * 16 + fr) * 64 + sw];
        #pragma unroll
        for (int m = 0; m < MR; ++m)
          #pragma unroll
          for (int j = 0; j < NR; ++j)
            acc[m][j] = __builtin_amdgcn_mfma_f32_16x16x32_bf16(af[m], bf[j], acc[m][j], 0, 0, 0);
      }
    }
    __builtin_amdgcn_sched_barrier(0);
    __builtin_amdgcn_s_barrier();
    buf ^= 1;
  }

  const int r4 = g4 * 4;
  #pragma unroll
  for (int m = 0; m < MR; ++m)
    #pragma unroll
    for (int j = 0; j < NR; ++j)
      #pragma unroll
      for (int v = 0; v < 4; ++v){
        size_t row = (size_t)(m0 + wr + m * 16 + r4 + v);
        size_t col = (size_t)(n0 + wc + j * 16 + fr);
        float x = acc[m][j][v];
        if (OUTF32){
          ((float*)C)[row * N + col] = x;
        } else {
          if (ROPE){
            int c = (int)col;
            int cj = c & 63;
            if (c < 2560 && cj < 32) x *= g[row * 16 + (cj >> 1)];
            if (c < 2048) x *= 0.18033688f;   // 0.125 * log2(e): softmax uses exp2 directly
          }
          ((u16*)C)[row * N + col] = f2b(x);
        }
      }
}

// ---------------- windowed attention, R8 = R7 + LDS diet for REAL 2-blocks/CU.
// R7's 75KB LDS (Vt 33.8 + P 43) almost certainly limited residency to 1 block/CU
// (usable LDS appears ~128KB from R1 occupancy data), leaving the stall-dominated
// critical path nothing to overlap with. R8 halves P (96 cols, stride 100,
// bank-verified free) and splits PV into two column phases sharing it:
//   write P[n0..5] -> lgkm fence -> barrier (Vt ready) -> PV kc0..2
//   -> write P[n6..9] into same buffer (WAR safe: in-wave DS order + aliasing)
//   -> lgkm fence -> PV kc3..4
// LDS 33.8+25.6 = 58KB -> 2 blocks/CU; block B's QK/softmax hides block A's
// staging drain + barrier (m114 mechanism that delivered the GEMM wins).
// Softmax: scores arrive pre-scaled by log2e (GEMM fold) -> exp2 direct.
#define PST 100
__global__ __launch_bounds__(512, 4) void k_attn(const u16* __restrict__ qkv, u16* __restrict__ aout){
  __shared__ __align__(16) u16 Vt[64 * 264];    // Vt[d][ck], 256 keys, ck = kk ^ ((d>>4)<<3)
  __shared__ __align__(16) u16 P[8 * 16 * PST]; // per-wave 16-row x 96-col half-slices
  const int tid = threadIdx.x;
  const int lane = tid & 63;
  const int w = tid >> 6;                      // 0..7
  const int id = blockIdx.x;                   // 0..511
  const int id2 = (id & 7) * 64 + (id >> 3);   // XCD x (id%8) -> contiguous chunk
  const int h = id2 >> 4;                      // head 0..31 (XCD x -> heads 4x..4x+3)
  const int q0 = (id2 & 15) * 128;             // q-block start
  const int kvh = h >> 2;                      // == id & 7
  const int kv0 = q0 - 128;                    // Vt column 0 = this key

  { // stage V transposed: 64 d x 256 kk, column-swizzled (4 iters x 512 threads).
    // No barrier here — writes drain under QK/softmax; barrier is before PV.
    const u16* Vg = qkv + VOFF + kvh * 64;
    #pragma unroll
    for (int i = 0; i < 4; ++i){
      int slot = i * 512 + tid;
      int kk = slot >> 3, d8 = (slot & 7) * 8;
      int ks = kv0 + kk; if (ks < 0) ks = 0;
      int ck = kk ^ ((d8 >> 4) << 3);          // d8..d8+7 share the same d>>4 block
      short8 v = *(const short8*)(Vg + (size_t)ks * QKV_LD + d8);
      #pragma unroll
      for (int e = 0; e < 8; ++e) Vt[(d8 + e) * 264 + ck] = (u16)v[e];
    }
  }

  const int fr = lane & 15;
  const int kc8 = (lane >> 4) * 8;
  const int r4 = (lane >> 4) * 4;
  const int tt = w >> 2;                       // which 64-row q-tile (0/1)
  const int wl = w & 3;                        // wave-in-tile 0..3
  const int nw0 = wl & ~1;                     // per-wave 32-aligned key-tile window
  const int c0 = nw0 * 16;
  const int qt = q0 + tt * 64;                 // this tile's first q row
  const int kbase = qt - 128;                  // tile-local key 0
  u16* Pw = P + w * 16 * PST;                  // this wave's P half-slice
  const u16* Qg = qkv + h * 64;
  const u16* Kg = qkv + KOFF + kvh * 64;

  short8 qa[2];
  {
    int qrow = qt + wl * 16 + fr;
    qa[0] = *(const short8*)(Qg + (size_t)qrow * QKV_LD + kc8);
    qa[1] = *(const short8*)(Qg + (size_t)qrow * QKV_LD + 32 + kc8);
  }

  f32x4 sc[10];
  __builtin_amdgcn_s_setprio(1);
  #pragma unroll
  for (int n = 0; n < 10; ++n){
    int kr = kbase + (nw0 + n) * 16 + fr;
    int krc = kr < 0 ? 0 : kr;
    short8 kb0 = *(const short8*)(Kg + (size_t)krc * QKV_LD + kc8);
    short8 kb1 = *(const short8*)(Kg + (size_t)krc * QKV_LD + 32 + kc8);
    f32x4 z = {0.f, 0.f, 0.f, 0.f};
    z = __builtin_amdgcn_mfma_f32_16x16x32_bf16(qa[0], kb0, z, 0, 0, 0);
    z = __builtin_amdgcn_mfma_f32_16x16x32_bf16(qa[1], kb1, z, 0, 0, 0);
    sc[n] = z;
  }
  __builtin_amdgcn_s_setprio(0);

  float inv_l[4];
  #pragma unroll
  for (int j = 0; j < 4; ++j){
    int q = qt + wl * 16 + r4 + j;
    float mx = -3.0e38f;
    #pragma unroll
    for (int n = 0; n < 10; ++n){
      int key = kbase + (nw0 + n) * 16 + fr;
      bool valid = (key >= 0) && (key <= q) && (key >= q - 128);
      float s = valid ? sc[n][j] : -1.0e30f;
      sc[n][j] = s;
      mx = fmaxf(mx, s);
    }
    mx = fmaxf(mx, __shfl_xor(mx, 1));
    mx = fmaxf(mx, __shfl_xor(mx, 2));
    mx = fmaxf(mx, __shfl_xor(mx, 4));
    mx = fmaxf(mx, __shfl_xor(mx, 8));
    float sum = 0.f;
    #pragma unroll
    for (int n = 0; n < 10; ++n){
      float pp = exp2f(sc[n][j] - mx);         // scores pre-scaled by log2e in GEMM
      sc[n][j] = pp;
      sum += pp;
    }
    sum += __shfl_xor(sum, 1);
    sum += __shfl_xor(sum, 2);
    sum += __shfl_xor(sum, 4);
    sum += __shfl_xor(sum, 8);
    inv_l[j] = 1.0f / sum;
  }

  // ---- phase A: P cols 0..95 (n-tiles 0..5)
  #pragma unroll
  for (int n = 0; n < 6; ++n)
    #pragma unroll
    for (int j = 0; j < 4; ++j)
      Pw[(r4 + j) * PST + n * 16 + fr] = f2b(sc[n][j]);

  // Drain this wave's P-A writes AND V-staging writes (same lgkm counter), then
  // cross-wave barrier so every wave's Vt contribution is visible before PV.
  asm volatile("s_waitcnt lgkmcnt(0)" ::: "memory");
  __syncthreads();

  f32x4 ov[4] = {};
  __builtin_amdgcn_s_setprio(1);
  #pragma unroll
  for (int kc = 0; kc < 3; ++kc){
    short8 pa = *(const short8*)&Pw[fr * PST + kc * 32 + kc8];
    #pragma unroll
    for (int f = 0; f < 4; ++f){
      short8 vb = *(const short8*)&Vt[(f * 16 + fr) * 264 + tt * 64 + c0 + kc * 32 + (kc8 ^ (f << 3))];
      ov[f] = __builtin_amdgcn_mfma_f32_16x16x32_bf16(pa, vb, ov[f], 0, 0, 0);
    }
  }
  __builtin_amdgcn_s_setprio(0);

  // ---- phase B: overwrite P buffer with cols 96..159 (n-tiles 6..9).
  // WAR vs phase-A reads is safe: same-wave DS ops execute in order, and the
  // compiler sees true aliasing (same buffer) so it preserves program order.
  #pragma unroll
  for (int n = 6; n < 10; ++n)
    #pragma unroll
    for (int j = 0; j < 4; ++j)
      Pw[(r4 + j) * PST + (n - 6) * 16 + fr] = f2b(sc[n][j]);

  asm volatile("s_waitcnt lgkmcnt(0)" ::: "memory");   // in-wave P-B RAW fence
  __builtin_amdgcn_sched_barrier(0);

  __builtin_amdgcn_s_setprio(1);
  #pragma unroll
  for (int kc = 3; kc < 5; ++kc){
    short8 pa = *(const short8*)&Pw[fr * PST + (kc - 3) * 32 + kc8];
    #pragma unroll
    for (int f = 0; f < 4; ++f){
      short8 vb = *(const short8*)&Vt[(f * 16 + fr) * 264 + tt * 64 + c0 + kc * 32 + (kc8 ^ (f << 3))];
      ov[f] = __builtin_amdgcn_mfma_f32_16x16x32_bf16(pa, vb, ov[f], 0, 0, 0);
    }
  }
  __builtin_amdgcn_s_setprio(0);

  #pragma unroll
  for (int f = 0; f < 4; ++f)
    #pragma unroll
    for (int j = 0; j < 4; ++j){
      int q = qt + wl * 16 + r4 + j;
      int col = h * 64 + f * 16 + fr;
      aout[(size_t)q * 2048 + col] = f2b(ov[f][j] * inv_l[j]);
    }
}

extern "C" void kernel_launch(void* const* d_in, const int* in_sizes, int n_in,
                              void* d_out, int out_size, void* d_ws, size_t ws_size,
                              hipStream_t stream) {
  const float* hidden = (const float*)d_in[0];
  const int*   pos    = (const int*)d_in[1];
  const float* Wq     = (const float*)d_in[2];
  const float* Wk     = (const float*)d_in[3];
  const float* Wv     = (const float*)d_in[4];
  const float* Wo     = (const float*)d_in[5];
  float* out = (float*)d_out;
  char* ws = (char*)d_ws;

  u16*  hb   = (u16*)(ws);                           // 8 MB; reused as aout after QKV GEMM
  u16*  Wcat = (u16*)(ws + ((size_t)8 << 20));       // 12 MB [Wq^T;Wk^T;Wv^T], LD=2048
  u16*  Wot  = (u16*)(ws + ((size_t)20 << 20));      // 8 MB Wo^T
  u16*  QKV  = (u16*)(ws + ((size_t)28 << 20));      // 12 MB
  float* gtab = (float*)(ws + ((size_t)40 << 20));   // 128 KB rope factors
  u16*  aout = hb;

  k_prep<<<6784, 256, 0, stream>>>(hidden, hb, pos, gtab, Wq, Wk, Wv, Wo, Wcat, Wot);
  k_gemm<0,1,128,96,2><<<512, 256, 0, stream>>>(hb, Wcat, QKV, gtab, 2048, 3072, 2048);
  k_attn<<<512, 512, 0, stream>>>(QKV, aout);
  k_gemm<1,0,64,128,3><<<512, 256, 0, stream>>>(aout, Wot, out, nullptr, 2048, 2048, 2048);
}

// Round 9
// 94.649 us; speedup vs baseline: 1.0348x; 1.0348x over previous
//
#include <hip/hip_runtime.h>

typedef unsigned short u16;
typedef short short8 __attribute__((ext_vector_type(8)));
typedef float f32x4 __attribute__((ext_vector_type(4)));

#define SLEN 2048
#define QKV_LD 3072
#define KOFF 2048
#define VOFF 2560

__device__ __forceinline__ u16 f2b(float f){
  unsigned u = __float_as_uint(f);
  u = u + 0x7FFFu + ((u >> 16) & 1u);     // RNE f32 -> bf16
  return (u16)(u >> 16);
}
__device__ __forceinline__ float b2f(u16 v){
  unsigned u = ((unsigned)v) << 16;
  return __uint_as_float(u);
}

__device__ __forceinline__ void gload16(const u16* g, u16* l){
  __builtin_amdgcn_global_load_lds((const __attribute__((address_space(1))) void*)g,
                                   (__attribute__((address_space(3))) void*)l, 16, 0, 0);
}

// ---------------- fused prep: hidden f2b (b<4096) + rope table (4096..4223) +
// Wq/Wk/Wv transposes. R9: Wo transpose MOVED to k_attn tail (only out-GEMM
// needs Wot, which launches after attn) -> prep grid 6784 -> 5760, -24MB traffic.
__global__ __launch_bounds__(256) void k_prep(const float* __restrict__ hidden, u16* __restrict__ hb,
                                              const int* __restrict__ pos, float* __restrict__ g,
                                              const float* __restrict__ Wq, const float* __restrict__ Wk,
                                              const float* __restrict__ Wv,
                                              u16* __restrict__ Wcat){
  __shared__ float tile[64][68];
  int b = blockIdx.x, t = threadIdx.x;
  if (b < 4096){
    int i = b * 256 + t;
    float4 v = ((const float4*)hidden)[i];
    ushort4 o;
    o.x = f2b(v.x); o.y = f2b(v.y); o.z = f2b(v.z); o.w = f2b(v.w);
    ((ushort4*)hb)[i] = o;
    return;
  }
  if (b < 4224){
    int idx = (b - 4096) * 256 + t;
    int s = idx >> 4, i = idx & 15;
    float inv = 1.0f / powf(150000.0f, (float)i / 16.0f);
    float wl = 6.283185307179586f / inv;
    float ratio = 4096.0f / wl;
    float alpha = (32.0f * ratio - 32.0f) / (1.0f - 32.0f);
    alpha = fminf(fmaxf(alpha, 0.0f), 1.0f);
    float invs = inv / powf(32.0f, alpha);
    float th = (float)pos[s] * invs;
    double tt = (double)th;
    g[idx] = (float)(cos(tt) + sin(tt));
    return;
  }
  b -= 4224;
  const float* W; int Nw, rowoff;
  if (b < 1024)      { W = Wq; Nw = 2048; rowoff = 0; }
  else if (b < 1280) { W = Wk; Nw = 512;  rowoff = 2048; b -= 1024; }
  else               { W = Wv; Nw = 512;  rowoff = 2560; b -= 1280; }
  const int kt = b & 31, nt = b >> 5;
  const int k0 = kt * 64, n0 = nt * 64;
  #pragma unroll
  for (int i = 0; i < 4; ++i){
    int slot = i * 256 + t;
    int r = slot >> 4, c4 = (slot & 15) * 4;
    float4 v = *(const float4*)&W[(size_t)(k0 + r) * Nw + n0 + c4];
    tile[r][c4] = v.x; tile[r][c4+1] = v.y; tile[r][c4+2] = v.z; tile[r][c4+3] = v.w;
  }
  __syncthreads();
  #pragma unroll
  for (int i = 0; i < 4; ++i){
    int slot = i * 256 + t;
    int nl = slot >> 4, k4 = (slot & 15) * 4;
    ushort4 o;
    o.x = f2b(tile[k4][nl]);   o.y = f2b(tile[k4+1][nl]);
    o.z = f2b(tile[k4+2][nl]); o.w = f2b(tile[k4+3][nl]);
    *(ushort4*)&Wcat[(size_t)(rowoff + n0 + nl) * 2048 + k0 + k4] = o;
  }
}

// ---------------- GEMM: parameterized BMxBN block, BK=64, 4 waves (2x2 wave grid),
// gload_lds-16B, XOR-8 source-side swizzle, counted vmcnt, XCD swizzle.
// 512-block grids = 2 blocks/CU, one clean co-residency round.
//   QKV (M2048,N3072): BM=128,BN=96, NBUF=2 (2-barrier dbuf; 57.3KB, R2-validated)
//   out (M2048,N2048): BM=64,BN=128, NBUF=3 (R9: 3-buffer rotation -> ONE barrier
//     per K-step; WAR proof: stage@k overwrites buffer computed @k-2, separated by
//     barrier@k-1. LDS 73.7KB -> still 2 blocks/CU. Halves barrier-drain count.)
template<int OUTF32, int ROPE, int BM, int BN, int MINW, int NBUF>
__global__ __launch_bounds__(256, MINW) void k_gemm(const u16* __restrict__ A, const u16* __restrict__ Bt,
                                                    void* __restrict__ C, const float* __restrict__ g,
                                                    int M, int N, int K){
  constexpr int AG = BM / 32;               // A gload_lds per wave per stage
  constexpr int BG = BN / 32;               // B gload_lds per wave per stage
  constexpr int ASZ = BM * 64;              // u16 per A buffer
  constexpr int BSZ = BN * 64;              // u16 per B buffer
  constexpr int MR = BM / 32;               // 16-row fragments per wave tile
  constexpr int NR = BN / 32;               // 16-col fragments per wave tile
  __shared__ __align__(16) u16 Smem[NBUF * (ASZ + BSZ)];
  const int tid = threadIdx.x;
  const int lane = tid & 63;
  const int w = tid >> 6;                   // 0..3
  const int wr = (w >> 1) * (BM / 2);
  const int wc = (w & 1) * (BN / 2);

  const int nbx = M / BM;
  const int nb  = nbx * (N / BN);
  const int q8  = nb >> 3;
  const int bo  = blockIdx.x;
  const int id2 = (bo & 7) * q8 + (bo >> 3);
  const int m0 = (id2 % nbx) * BM;
  const int n0 = (id2 / nbx) * BN;

  const int rl = lane >> 3;
  const int sc = ((lane & 7) ^ rl) << 3;
  const u16* Ag[AG]; const u16* Bg[BG];
  int Ad[AG], Bd[BG];
  #pragma unroll
  for (int i = 0; i < AG; ++i){
    int row0 = w * (AG * 8) + i * 8;        // A rows 0..BM-1 across 4 waves
    Ag[i] = A + (size_t)(m0 + row0 + rl) * K + sc;
    Ad[i] = row0 * 64;
  }
  #pragma unroll
  for (int i = 0; i < BG; ++i){
    int row0 = w * (BG * 8) + i * 8;        // B rows 0..BN-1 across 4 waves
    Bg[i] = Bt + (size_t)(n0 + row0 + rl) * K + sc;
    Bd[i] = NBUF * ASZ + row0 * 64;
  }

  const int fr = lane & 15;
  const int g4 = lane >> 4;

  f32x4 acc[MR][NR] = {};

  auto stage = [&](int buf, int k0){
    #pragma unroll
    for (int i = 0; i < AG; ++i) gload16(Ag[i] + k0, Smem + Ad[i] + buf * ASZ);
    #pragma unroll
    for (int i = 0; i < BG; ++i) gload16(Bg[i] + k0, Smem + Bd[i] + buf * BSZ);
  };

  stage(0, 0);
  int buf = 0;
  const int nt = K >> 6;
  for (int kt = 0; kt < nt; ++kt){
    int nxt = (buf + 1 == NBUF) ? 0 : buf + 1;
    if (kt + 1 < nt){
      stage(nxt, (kt + 1) << 6);
      if constexpr (AG + BG == 6)      asm volatile("s_waitcnt vmcnt(6)" ::: "memory");
      else if constexpr (AG + BG == 7) asm volatile("s_waitcnt vmcnt(7)" ::: "memory");
      else                             asm volatile("s_waitcnt vmcnt(8)" ::: "memory");
    } else {
      asm volatile("s_waitcnt vmcnt(0)" ::: "memory");
    }
    __builtin_amdgcn_s_barrier();
    __builtin_amdgcn_sched_barrier(0);
    {
      const u16* Asb = Smem + buf * ASZ;
      const u16* Bsb = Smem + NBUF * ASZ + buf * BSZ;
      #pragma unroll
      for (int kk = 0; kk < 2; ++kk){
        const int sw = (((kk * 4 + g4)) ^ (fr & 7)) << 3;
        short8 af[MR], bf[NR];
        #pragma unroll
        for (int m = 0; m < MR; ++m)
          af[m] = *(const short8*)&Asb[(wr + m * 16 + fr) * 64 + sw];
        #pragma unroll
        for (int j = 0; j < NR; ++j)
          bf[j] = *(const short8*)&Bsb[(wc + j * 16 + fr) * 64 + sw];
        #pragma unroll
        for (int m = 0; m < MR; ++m)
          #pragma unroll
          for (int j = 0; j < NR; ++j)
            acc[m][j] = __builtin_amdgcn_mfma_f32_16x16x32_bf16(af[m], bf[j], acc[m][j], 0, 0, 0);
      }
    }
    if constexpr (NBUF == 2){
      __builtin_amdgcn_sched_barrier(0);
      __builtin_amdgcn_s_barrier();
    }
    buf = nxt;
  }

  const int r4 = g4 * 4;
  #pragma unroll
  for (int m = 0; m < MR; ++m)
    #pragma unroll
    for (int j = 0; j < NR; ++j)
      #pragma unroll
      for (int v = 0; v < 4; ++v){
        size_t row = (size_t)(m0 + wr + m * 16 + r4 + v);
        size_t col = (size_t)(n0 + wc + j * 16 + fr);
        float x = acc[m][j][v];
        if (OUTF32){
          ((float*)C)[row * N + col] = x;
        } else {
          if (ROPE){
            int c = (int)col;
            int cj = c & 63;
            if (c < 2560 && cj < 32) x *= g[row * 16 + (cj >> 1)];
            if (c < 2048) x *= 0.18033688f;   // 0.125 * log2(e): softmax uses exp2 directly
          }
          ((u16*)C)[row * N + col] = f2b(x);
        }
      }
}

// ---------------- windowed attention, R9 = R7 structure (validated best: full P,
// single PV phase, late barrier, setprio, exp2-direct) + Wo-transpose tail:
// each block transposes 2 of the 1024 Wo 64x64 tiles after its output store,
// reusing Vt's LDS (17.4KB <= 33.8KB, barrier-guarded). The 24MB of transpose
// traffic rides attn's idle HBM BW and the ragged block tail; out-GEMM (next
// dispatch) is ordered after attn by the stream.
#define PST 168
__global__ __launch_bounds__(512, 4) void k_attn(const u16* __restrict__ qkv, u16* __restrict__ aout,
                                                 const float* __restrict__ Wo, u16* __restrict__ Wot){
  __shared__ __align__(16) u16 Vt[64 * 264];    // Vt[d][ck], 256 keys, ck = kk ^ ((d>>4)<<3)
  __shared__ __align__(16) u16 P[8 * 16 * PST]; // per-wave 16-row slices
  const int tid = threadIdx.x;
  const int lane = tid & 63;
  const int w = tid >> 6;                      // 0..7
  const int id = blockIdx.x;                   // 0..511
  const int id2 = (id & 7) * 64 + (id >> 3);   // XCD x (id%8) -> contiguous chunk
  const int h = id2 >> 4;                      // head 0..31 (XCD x -> heads 4x..4x+3)
  const int q0 = (id2 & 15) * 128;             // q-block start
  const int kvh = h >> 2;                      // == id & 7
  const int kv0 = q0 - 128;                    // Vt column 0 = this key

  { // stage V transposed: 64 d x 256 kk, column-swizzled (4 iters x 512 threads).
    // No barrier here — writes drain under QK/softmax; barrier is before PV.
    const u16* Vg = qkv + VOFF + kvh * 64;
    #pragma unroll
    for (int i = 0; i < 4; ++i){
      int slot = i * 512 + tid;
      int kk = slot >> 3, d8 = (slot & 7) * 8;
      int ks = kv0 + kk; if (ks < 0) ks = 0;
      int ck = kk ^ ((d8 >> 4) << 3);          // d8..d8+7 share the same d>>4 block
      short8 v = *(const short8*)(Vg + (size_t)ks * QKV_LD + d8);
      #pragma unroll
      for (int e = 0; e < 8; ++e) Vt[(d8 + e) * 264 + ck] = (u16)v[e];
    }
  }

  const int fr = lane & 15;
  const int kc8 = (lane >> 4) * 8;
  const int r4 = (lane >> 4) * 4;
  const int tt = w >> 2;                       // which 64-row q-tile (0/1)
  const int wl = w & 3;                        // wave-in-tile 0..3
  const int nw0 = wl & ~1;                     // per-wave 32-aligned key-tile window
  const int c0 = nw0 * 16;
  const int qt = q0 + tt * 64;                 // this tile's first q row
  const int kbase = qt - 128;                  // tile-local key 0
  u16* Pw = P + w * 16 * PST;                  // this wave's P slice
  const u16* Qg = qkv + h * 64;
  const u16* Kg = qkv + KOFF + kvh * 64;

  short8 qa[2];
  {
    int qrow = qt + wl * 16 + fr;
    qa[0] = *(const short8*)(Qg + (size_t)qrow * QKV_LD + kc8);
    qa[1] = *(const short8*)(Qg + (size_t)qrow * QKV_LD + 32 + kc8);
  }

  f32x4 sc[10];
  __builtin_amdgcn_s_setprio(1);
  #pragma unroll
  for (int n = 0; n < 10; ++n){
    int kr = kbase + (nw0 + n) * 16 + fr;
    int krc = kr < 0 ? 0 : kr;
    short8 kb0 = *(const short8*)(Kg + (size_t)krc * QKV_LD + kc8);
    short8 kb1 = *(const short8*)(Kg + (size_t)krc * QKV_LD + 32 + kc8);
    f32x4 z = {0.f, 0.f, 0.f, 0.f};
    z = __builtin_amdgcn_mfma_f32_16x16x32_bf16(qa[0], kb0, z, 0, 0, 0);
    z = __builtin_amdgcn_mfma_f32_16x16x32_bf16(qa[1], kb1, z, 0, 0, 0);
    sc[n] = z;
  }
  __builtin_amdgcn_s_setprio(0);

  float inv_l[4];
  #pragma unroll
  for (int j = 0; j < 4; ++j){
    int q = qt + wl * 16 + r4 + j;
    float mx = -3.0e38f;
    #pragma unroll
    for (int n = 0; n < 10; ++n){
      int key = kbase + (nw0 + n) * 16 + fr;
      bool valid = (key >= 0) && (key <= q) && (key >= q - 128);
      float s = valid ? sc[n][j] : -1.0e30f;
      sc[n][j] = s;
      mx = fmaxf(mx, s);
    }
    mx = fmaxf(mx, __shfl_xor(mx, 1));
    mx = fmaxf(mx, __shfl_xor(mx, 2));
    mx = fmaxf(mx, __shfl_xor(mx, 4));
    mx = fmaxf(mx, __shfl_xor(mx, 8));
    float sum = 0.f;
    #pragma unroll
    for (int n = 0; n < 10; ++n){
      float pp = exp2f(sc[n][j] - mx);         // scores pre-scaled by log2e in GEMM
      sc[n][j] = pp;
      sum += pp;
    }
    sum += __shfl_xor(sum, 1);
    sum += __shfl_xor(sum, 2);
    sum += __shfl_xor(sum, 4);
    sum += __shfl_xor(sum, 8);
    inv_l[j] = 1.0f / sum;
  }

  #pragma unroll
  for (int n = 0; n < 10; ++n)
    #pragma unroll
    for (int j = 0; j < 4; ++j)
      Pw[(r4 + j) * PST + n * 16 + fr] = f2b(sc[n][j]);

  // Drain this wave's P-writes AND V-staging writes (same lgkm counter), then
  // cross-wave barrier so every wave's Vt contribution is visible before PV.
  asm volatile("s_waitcnt lgkmcnt(0)" ::: "memory");
  __syncthreads();

  f32x4 ov[4] = {};
  __builtin_amdgcn_s_setprio(1);
  #pragma unroll
  for (int kc = 0; kc < 5; ++kc){
    short8 pa = *(const short8*)&Pw[fr * PST + kc * 32 + kc8];
    #pragma unroll
    for (int f = 0; f < 4; ++f){
      short8 vb = *(const short8*)&Vt[(f * 16 + fr) * 264 + tt * 64 + c0 + kc * 32 + (kc8 ^ (f << 3))];
      ov[f] = __builtin_amdgcn_mfma_f32_16x16x32_bf16(pa, vb, ov[f], 0, 0, 0);
    }
  }
  __builtin_amdgcn_s_setprio(0);

  #pragma unroll
  for (int f = 0; f < 4; ++f)
    #pragma unroll
    for (int j = 0; j < 4; ++j){
      int q = qt + wl * 16 + r4 + j;
      int col = h * 64 + f * 16 + fr;
      aout[(size_t)q * 2048 + col] = f2b(ov[f][j] * inv_l[j]);
    }

  // ---- Wo-transpose tail: 2 of 1024 64x64 tiles per block, LDS reused from Vt.
  __syncthreads();                             // all waves done reading Vt/P
  float (*tf)[68] = (float(*)[68])Vt;          // 17.4KB <= 33.8KB
  #pragma unroll
  for (int tix = 0; tix < 2; ++tix){
    int tile = id * 2 + tix;
    int kt2 = tile & 31, nt2 = tile >> 5;
    int k0 = kt2 * 64, n0 = nt2 * 64;
    #pragma unroll
    for (int i = 0; i < 2; ++i){
      int slot = i * 512 + tid;
      int r = slot >> 4, c4 = (slot & 15) * 4;
      float4 v = *(const float4*)&Wo[(size_t)(k0 + r) * 2048 + n0 + c4];
      tf[r][c4] = v.x; tf[r][c4+1] = v.y; tf[r][c4+2] = v.z; tf[r][c4+3] = v.w;
    }
    __syncthreads();
    #pragma unroll
    for (int i = 0; i < 2; ++i){
      int slot = i * 512 + tid;
      int nl = slot >> 4, k4 = (slot & 15) * 4;
      ushort4 o;
      o.x = f2b(tf[k4][nl]);   o.y = f2b(tf[k4+1][nl]);
      o.z = f2b(tf[k4+2][nl]); o.w = f2b(tf[k4+3][nl]);
      *(ushort4*)&Wot[(size_t)(n0 + nl) * 2048 + k0 + k4] = o;
    }
    __syncthreads();
  }
}

extern "C" void kernel_launch(void* const* d_in, const int* in_sizes, int n_in,
                              void* d_out, int out_size, void* d_ws, size_t ws_size,
                              hipStream_t stream) {
  const float* hidden = (const float*)d_in[0];
  const int*   pos    = (const int*)d_in[1];
  const float* Wq     = (const float*)d_in[2];
  const float* Wk     = (const float*)d_in[3];
  const float* Wv     = (const float*)d_in[4];
  const float* Wo     = (const float*)d_in[5];
  float* out = (float*)d_out;
  char* ws = (char*)d_ws;

  u16*  hb   = (u16*)(ws);                           // 8 MB; reused as aout after QKV GEMM
  u16*  Wcat = (u16*)(ws + ((size_t)8 << 20));       // 12 MB [Wq^T;Wk^T;Wv^T], LD=2048
  u16*  Wot  = (u16*)(ws + ((size_t)20 << 20));      // 8 MB Wo^T (written by k_attn tail)
  u16*  QKV  = (u16*)(ws + ((size_t)28 << 20));      // 12 MB
  float* gtab = (float*)(ws + ((size_t)40 << 20));   // 128 KB rope factors
  u16*  aout = hb;

  k_prep<<<5760, 256, 0, stream>>>(hidden, hb, pos, gtab, Wq, Wk, Wv, Wcat);
  k_gemm<0,1,128,96,2,2><<<512, 256, 0, stream>>>(hb, Wcat, QKV, gtab, 2048, 3072, 2048);
  k_attn<<<512, 512, 0, stream>>>(QKV, aout, Wo, Wot);
  k_gemm<1,0,64,128,2,3><<<512, 256, 0, stream>>>(aout, Wot, out, nullptr, 2048, 2048, 2048);
}

// Round 10
// 93.114 us; speedup vs baseline: 1.0519x; 1.0165x over previous
//
#include <hip/hip_runtime.h>

typedef unsigned short u16;
typedef short short8 __attribute__((ext_vector_type(8)));
typedef float f32x4 __attribute__((ext_vector_type(4)));

#define SLEN 2048
#define QKV_LD 3072
#define KOFF 2048
#define VOFF 2560

__device__ __forceinline__ u16 f2b(float f){
  unsigned u = __float_as_uint(f);
  u = u + 0x7FFFu + ((u >> 16) & 1u);     // RNE f32 -> bf16
  return (u16)(u >> 16);
}
__device__ __forceinline__ float b2f(u16 v){
  unsigned u = ((unsigned)v) << 16;
  return __uint_as_float(u);
}

__device__ __forceinline__ void gload16(const u16* g, u16* l){
  __builtin_amdgcn_global_load_lds((const __attribute__((address_space(1))) void*)g,
                                   (__attribute__((address_space(3))) void*)l, 16, 0, 0);
}

// ---------------- fused prep: hidden f2b (b<4096) + rope table (4096..4223) +
// Wq/Wk/Wv transposes. Wo transpose lives in k_attn tail (R9).
__global__ __launch_bounds__(256) void k_prep(const float* __restrict__ hidden, u16* __restrict__ hb,
                                              const int* __restrict__ pos, float* __restrict__ g,
                                              const float* __restrict__ Wq, const float* __restrict__ Wk,
                                              const float* __restrict__ Wv,
                                              u16* __restrict__ Wcat){
  __shared__ float tile[64][68];
  int b = blockIdx.x, t = threadIdx.x;
  if (b < 4096){
    int i = b * 256 + t;
    float4 v = ((const float4*)hidden)[i];
    ushort4 o;
    o.x = f2b(v.x); o.y = f2b(v.y); o.z = f2b(v.z); o.w = f2b(v.w);
    ((ushort4*)hb)[i] = o;
    return;
  }
  if (b < 4224){
    int idx = (b - 4096) * 256 + t;
    int s = idx >> 4, i = idx & 15;
    float inv = 1.0f / powf(150000.0f, (float)i / 16.0f);
    float wl = 6.283185307179586f / inv;
    float ratio = 4096.0f / wl;
    float alpha = (32.0f * ratio - 32.0f) / (1.0f - 32.0f);
    alpha = fminf(fmaxf(alpha, 0.0f), 1.0f);
    float invs = inv / powf(32.0f, alpha);
    float th = (float)pos[s] * invs;
    double tt = (double)th;
    g[idx] = (float)(cos(tt) + sin(tt));
    return;
  }
  b -= 4224;
  const float* W; int Nw, rowoff;
  if (b < 1024)      { W = Wq; Nw = 2048; rowoff = 0; }
  else if (b < 1280) { W = Wk; Nw = 512;  rowoff = 2048; b -= 1024; }
  else               { W = Wv; Nw = 512;  rowoff = 2560; b -= 1280; }
  const int kt = b & 31, nt = b >> 5;
  const int k0 = kt * 64, n0 = nt * 64;
  #pragma unroll
  for (int i = 0; i < 4; ++i){
    int slot = i * 256 + t;
    int r = slot >> 4, c4 = (slot & 15) * 4;
    float4 v = *(const float4*)&W[(size_t)(k0 + r) * Nw + n0 + c4];
    tile[r][c4] = v.x; tile[r][c4+1] = v.y; tile[r][c4+2] = v.z; tile[r][c4+3] = v.w;
  }
  __syncthreads();
  #pragma unroll
  for (int i = 0; i < 4; ++i){
    int slot = i * 256 + t;
    int nl = slot >> 4, k4 = (slot & 15) * 4;
    ushort4 o;
    o.x = f2b(tile[k4][nl]);   o.y = f2b(tile[k4+1][nl]);
    o.z = f2b(tile[k4+2][nl]); o.w = f2b(tile[k4+3][nl]);
    *(ushort4*)&Wcat[(size_t)(rowoff + n0 + nl) * 2048 + k0 + k4] = o;
  }
}

// ---------------- GEMM: parameterized BMxBN block, BK=64, 4 waves (2x2 wave grid),
// gload_lds-16B, XOR-8 source-side swizzle, XCD swizzle. 512-block-ish grids.
// R10: BOTH paths are now single-barrier per K-step.
//   NBUF=2 (QKV, BM128xBN96, 57.3KB, 2 blocks/CU): stage moved AFTER the barrier:
//     iter k: vmcnt(0) -> barrier -> stage(k+1) -> compute(k)
//     RAW: each wave drains its own stage(k) at vmcnt(0) pre-barrier -> post-barrier
//       all staging visible. WAR: stage(k+1) is post-barrier@k; every wave finished
//       compute(k-1) (ds_reads lgkm-drained before its last MFMA) pre-barrier@k.
//     vmcnt(0) is cheap: stage(k) had all of compute(k-1) to land (~300cyc vs L2 200).
//   NBUF=3 (out, BM64xBN128, 73.7KB, 2 blocks/CU): R9-validated rotation,
//     stage-before-barrier with counted vmcnt.
template<int OUTF32, int ROPE, int BM, int BN, int MINW, int NBUF>
__global__ __launch_bounds__(256, MINW) void k_gemm(const u16* __restrict__ A, const u16* __restrict__ Bt,
                                                    void* __restrict__ C, const float* __restrict__ g,
                                                    int M, int N, int K){
  constexpr int AG = BM / 32;               // A gload_lds per wave per stage
  constexpr int BG = BN / 32;               // B gload_lds per wave per stage
  constexpr int ASZ = BM * 64;              // u16 per A buffer
  constexpr int BSZ = BN * 64;              // u16 per B buffer
  constexpr int MR = BM / 32;               // 16-row fragments per wave tile
  constexpr int NR = BN / 32;               // 16-col fragments per wave tile
  __shared__ __align__(16) u16 Smem[NBUF * (ASZ + BSZ)];
  const int tid = threadIdx.x;
  const int lane = tid & 63;
  const int w = tid >> 6;                   // 0..3
  const int wr = (w >> 1) * (BM / 2);
  const int wc = (w & 1) * (BN / 2);

  const int nbx = M / BM;
  const int nb  = nbx * (N / BN);
  const int q8  = nb >> 3;
  const int bo  = blockIdx.x;
  const int id2 = (bo & 7) * q8 + (bo >> 3);
  const int m0 = (id2 % nbx) * BM;
  const int n0 = (id2 / nbx) * BN;

  const int rl = lane >> 3;
  const int sc = ((lane & 7) ^ rl) << 3;
  const u16* Ag[AG]; const u16* Bg[BG];
  int Ad[AG], Bd[BG];
  #pragma unroll
  for (int i = 0; i < AG; ++i){
    int row0 = w * (AG * 8) + i * 8;        // A rows 0..BM-1 across 4 waves
    Ag[i] = A + (size_t)(m0 + row0 + rl) * K + sc;
    Ad[i] = row0 * 64;
  }
  #pragma unroll
  for (int i = 0; i < BG; ++i){
    int row0 = w * (BG * 8) + i * 8;        // B rows 0..BN-1 across 4 waves
    Bg[i] = Bt + (size_t)(n0 + row0 + rl) * K + sc;
    Bd[i] = NBUF * ASZ + row0 * 64;
  }

  const int fr = lane & 15;
  const int g4 = lane >> 4;

  f32x4 acc[MR][NR] = {};

  auto stage = [&](int buf, int k0){
    #pragma unroll
    for (int i = 0; i < AG; ++i) gload16(Ag[i] + k0, Smem + Ad[i] + buf * ASZ);
    #pragma unroll
    for (int i = 0; i < BG; ++i) gload16(Bg[i] + k0, Smem + Bd[i] + buf * BSZ);
  };

  auto compute = [&](int buf){
    const u16* Asb = Smem + buf * ASZ;
    const u16* Bsb = Smem + NBUF * ASZ + buf * BSZ;
    #pragma unroll
    for (int kk = 0; kk < 2; ++kk){
      const int sw = (((kk * 4 + g4)) ^ (fr & 7)) << 3;
      short8 af[MR], bf[NR];
      #pragma unroll
      for (int m = 0; m < MR; ++m)
        af[m] = *(const short8*)&Asb[(wr + m * 16 + fr) * 64 + sw];
      #pragma unroll
      for (int j = 0; j < NR; ++j)
        bf[j] = *(const short8*)&Bsb[(wc + j * 16 + fr) * 64 + sw];
      #pragma unroll
      for (int m = 0; m < MR; ++m)
        #pragma unroll
        for (int j = 0; j < NR; ++j)
          acc[m][j] = __builtin_amdgcn_mfma_f32_16x16x32_bf16(af[m], bf[j], acc[m][j], 0, 0, 0);
    }
  };

  stage(0, 0);
  int buf = 0;
  const int nt = K >> 6;
  if constexpr (NBUF == 2){
    for (int kt = 0; kt < nt; ++kt){
      asm volatile("s_waitcnt vmcnt(0)" ::: "memory");   // drain own stage(kt)
      __builtin_amdgcn_s_barrier();                      // all waves' stage(kt) visible
      __builtin_amdgcn_sched_barrier(0);
      if (kt + 1 < nt) stage(buf ^ 1, (kt + 1) << 6);    // WAR-safe: post-barrier
      compute(buf);
      buf ^= 1;
    }
  } else {
    for (int kt = 0; kt < nt; ++kt){
      int nxt = (buf + 1 == NBUF) ? 0 : buf + 1;
      if (kt + 1 < nt){
        stage(nxt, (kt + 1) << 6);
        if constexpr (AG + BG == 6)      asm volatile("s_waitcnt vmcnt(6)" ::: "memory");
        else if constexpr (AG + BG == 7) asm volatile("s_waitcnt vmcnt(7)" ::: "memory");
        else                             asm volatile("s_waitcnt vmcnt(8)" ::: "memory");
      } else {
        asm volatile("s_waitcnt vmcnt(0)" ::: "memory");
      }
      __builtin_amdgcn_s_barrier();
      __builtin_amdgcn_sched_barrier(0);
      compute(buf);
      buf = nxt;
    }
  }

  const int r4 = g4 * 4;
  #pragma unroll
  for (int m = 0; m < MR; ++m)
    #pragma unroll
    for (int j = 0; j < NR; ++j)
      #pragma unroll
      for (int v = 0; v < 4; ++v){
        size_t row = (size_t)(m0 + wr + m * 16 + r4 + v);
        size_t col = (size_t)(n0 + wc + j * 16 + fr);
        float x = acc[m][j][v];
        if (OUTF32){
          ((float*)C)[row * N + col] = x;
        } else {
          if (ROPE){
            int c = (int)col;
            int cj = c & 63;
            if (c < 2560 && cj < 32) x *= g[row * 16 + (cj >> 1)];
            if (c < 2048) x *= 0.18033688f;   // 0.125 * log2(e): softmax uses exp2 directly
          }
          ((u16*)C)[row * N + col] = f2b(x);
        }
      }
}

// ---------------- windowed attention, R9-validated: R7 structure (full P, single
// PV phase, late barrier, setprio, exp2-direct) + Wo-transpose tail.
#define PST 168
__global__ __launch_bounds__(512, 4) void k_attn(const u16* __restrict__ qkv, u16* __restrict__ aout,
                                                 const float* __restrict__ Wo, u16* __restrict__ Wot){
  __shared__ __align__(16) u16 Vt[64 * 264];    // Vt[d][ck], 256 keys, ck = kk ^ ((d>>4)<<3)
  __shared__ __align__(16) u16 P[8 * 16 * PST]; // per-wave 16-row slices
  const int tid = threadIdx.x;
  const int lane = tid & 63;
  const int w = tid >> 6;                      // 0..7
  const int id = blockIdx.x;                   // 0..511
  const int id2 = (id & 7) * 64 + (id >> 3);   // XCD x (id%8) -> contiguous chunk
  const int h = id2 >> 4;                      // head 0..31 (XCD x -> heads 4x..4x+3)
  const int q0 = (id2 & 15) * 128;             // q-block start
  const int kvh = h >> 2;                      // == id & 7
  const int kv0 = q0 - 128;                    // Vt column 0 = this key

  { // stage V transposed: 64 d x 256 kk, column-swizzled (4 iters x 512 threads).
    // No barrier here — writes drain under QK/softmax; barrier is before PV.
    const u16* Vg = qkv + VOFF + kvh * 64;
    #pragma unroll
    for (int i = 0; i < 4; ++i){
      int slot = i * 512 + tid;
      int kk = slot >> 3, d8 = (slot & 7) * 8;
      int ks = kv0 + kk; if (ks < 0) ks = 0;
      int ck = kk ^ ((d8 >> 4) << 3);          // d8..d8+7 share the same d>>4 block
      short8 v = *(const short8*)(Vg + (size_t)ks * QKV_LD + d8);
      #pragma unroll
      for (int e = 0; e < 8; ++e) Vt[(d8 + e) * 264 + ck] = (u16)v[e];
    }
  }

  const int fr = lane & 15;
  const int kc8 = (lane >> 4) * 8;
  const int r4 = (lane >> 4) * 4;
  const int tt = w >> 2;                       // which 64-row q-tile (0/1)
  const int wl = w & 3;                        // wave-in-tile 0..3
  const int nw0 = wl & ~1;                     // per-wave 32-aligned key-tile window
  const int c0 = nw0 * 16;
  const int qt = q0 + tt * 64;                 // this tile's first q row
  const int kbase = qt - 128;                  // tile-local key 0
  u16* Pw = P + w * 16 * PST;                  // this wave's P slice
  const u16* Qg = qkv + h * 64;
  const u16* Kg = qkv + KOFF + kvh * 64;

  short8 qa[2];
  {
    int qrow = qt + wl * 16 + fr;
    qa[0] = *(const short8*)(Qg + (size_t)qrow * QKV_LD + kc8);
    qa[1] = *(const short8*)(Qg + (size_t)qrow * QKV_LD + 32 + kc8);
  }

  f32x4 sc[10];
  __builtin_amdgcn_s_setprio(1);
  #pragma unroll
  for (int n = 0; n < 10; ++n){
    int kr = kbase + (nw0 + n) * 16 + fr;
    int krc = kr < 0 ? 0 : kr;
    short8 kb0 = *(const short8*)(Kg + (size_t)krc * QKV_LD + kc8);
    short8 kb1 = *(const short8*)(Kg + (size_t)krc * QKV_LD + 32 + kc8);
    f32x4 z = {0.f, 0.f, 0.f, 0.f};
    z = __builtin_amdgcn_mfma_f32_16x16x32_bf16(qa[0], kb0, z, 0, 0, 0);
    z = __builtin_amdgcn_mfma_f32_16x16x32_bf16(qa[1], kb1, z, 0, 0, 0);
    sc[n] = z;
  }
  __builtin_amdgcn_s_setprio(0);

  float inv_l[4];
  #pragma unroll
  for (int j = 0; j < 4; ++j){
    int q = qt + wl * 16 + r4 + j;
    float mx = -3.0e38f;
    #pragma unroll
    for (int n = 0; n < 10; ++n){
      int key = kbase + (nw0 + n) * 16 + fr;
      bool valid = (key >= 0) && (key <= q) && (key >= q - 128);
      float s = valid ? sc[n][j] : -1.0e30f;
      sc[n][j] = s;
      mx = fmaxf(mx, s);
    }
    mx = fmaxf(mx, __shfl_xor(mx, 1));
    mx = fmaxf(mx, __shfl_xor(mx, 2));
    mx = fmaxf(mx, __shfl_xor(mx, 4));
    mx = fmaxf(mx, __shfl_xor(mx, 8));
    float sum = 0.f;
    #pragma unroll
    for (int n = 0; n < 10; ++n){
      float pp = exp2f(sc[n][j] - mx);         // scores pre-scaled by log2e in GEMM
      sc[n][j] = pp;
      sum += pp;
    }
    sum += __shfl_xor(sum, 1);
    sum += __shfl_xor(sum, 2);
    sum += __shfl_xor(sum, 4);
    sum += __shfl_xor(sum, 8);
    inv_l[j] = 1.0f / sum;
  }

  #pragma unroll
  for (int n = 0; n < 10; ++n)
    #pragma unroll
    for (int j = 0; j < 4; ++j)
      Pw[(r4 + j) * PST + n * 16 + fr] = f2b(sc[n][j]);

  // Drain this wave's P-writes AND V-staging writes (same lgkm counter), then
  // cross-wave barrier so every wave's Vt contribution is visible before PV.
  asm volatile("s_waitcnt lgkmcnt(0)" ::: "memory");
  __syncthreads();

  f32x4 ov[4] = {};
  __builtin_amdgcn_s_setprio(1);
  #pragma unroll
  for (int kc = 0; kc < 5; ++kc){
    short8 pa = *(const short8*)&Pw[fr * PST + kc * 32 + kc8];
    #pragma unroll
    for (int f = 0; f < 4; ++f){
      short8 vb = *(const short8*)&Vt[(f * 16 + fr) * 264 + tt * 64 + c0 + kc * 32 + (kc8 ^ (f << 3))];
      ov[f] = __builtin_amdgcn_mfma_f32_16x16x32_bf16(pa, vb, ov[f], 0, 0, 0);
    }
  }
  __builtin_amdgcn_s_setprio(0);

  #pragma unroll
  for (int f = 0; f < 4; ++f)
    #pragma unroll
    for (int j = 0; j < 4; ++j){
      int q = qt + wl * 16 + r4 + j;
      int col = h * 64 + f * 16 + fr;
      aout[(size_t)q * 2048 + col] = f2b(ov[f][j] * inv_l[j]);
    }

  // ---- Wo-transpose tail: 2 of 1024 64x64 tiles per block, LDS reused from Vt.
  __syncthreads();                             // all waves done reading Vt/P
  float (*tf)[68] = (float(*)[68])Vt;          // 17.4KB <= 33.8KB
  #pragma unroll
  for (int tix = 0; tix < 2; ++tix){
    int tile = id * 2 + tix;
    int kt2 = tile & 31, nt2 = tile >> 5;
    int k0 = kt2 * 64, n0 = nt2 * 64;
    #pragma unroll
    for (int i = 0; i < 2; ++i){
      int slot = i * 512 + tid;
      int r = slot >> 4, c4 = (slot & 15) * 4;
      float4 v = *(const float4*)&Wo[(size_t)(k0 + r) * 2048 + n0 + c4];
      tf[r][c4] = v.x; tf[r][c4+1] = v.y; tf[r][c4+2] = v.z; tf[r][c4+3] = v.w;
    }
    __syncthreads();
    #pragma unroll
    for (int i = 0; i < 2; ++i){
      int slot = i * 512 + tid;
      int nl = slot >> 4, k4 = (slot & 15) * 4;
      ushort4 o;
      o.x = f2b(tf[k4][nl]);   o.y = f2b(tf[k4+1][nl]);
      o.z = f2b(tf[k4+2][nl]); o.w = f2b(tf[k4+3][nl]);
      *(ushort4*)&Wot[(size_t)(n0 + nl) * 2048 + k0 + k4] = o;
    }
    __syncthreads();
  }
}

extern "C" void kernel_launch(void* const* d_in, const int* in_sizes, int n_in,
                              void* d_out, int out_size, void* d_ws, size_t ws_size,
                              hipStream_t stream) {
  const float* hidden = (const float*)d_in[0];
  const int*   pos    = (const int*)d_in[1];
  const float* Wq     = (const float*)d_in[2];
  const float* Wk     = (const float*)d_in[3];
  const float* Wv     = (const float*)d_in[4];
  const float* Wo     = (const float*)d_in[5];
  float* out = (float*)d_out;
  char* ws = (char*)d_ws;

  u16*  hb   = (u16*)(ws);                           // 8 MB; reused as aout after QKV GEMM
  u16*  Wcat = (u16*)(ws + ((size_t)8 << 20));       // 12 MB [Wq^T;Wk^T;Wv^T], LD=2048
  u16*  Wot  = (u16*)(ws + ((size_t)20 << 20));      // 8 MB Wo^T (written by k_attn tail)
  u16*  QKV  = (u16*)(ws + ((size_t)28 << 20));      // 12 MB
  float* gtab = (float*)(ws + ((size_t)40 << 20));   // 128 KB rope factors
  u16*  aout = hb;

  k_prep<<<5760, 256, 0, stream>>>(hidden, hb, pos, gtab, Wq, Wk, Wv, Wcat);
  k_gemm<0,1,128,96,2,2><<<512, 256, 0, stream>>>(hb, Wcat, QKV, gtab, 2048, 3072, 2048);
  k_attn<<<512, 512, 0, stream>>>(QKV, aout, Wo, Wot);
  k_gemm<1,0,64,128,2,3><<<512, 256, 0, stream>>>(aout, Wot, out, nullptr, 2048, 2048, 2048);
}